// Round 9
// baseline (644.466 us; speedup 1.0000x reference)
//
#include <hip/hip_runtime.h>

// x[2048,64,2] -> MLP(2->16 relu ->16) -> 8x LSTM(H=64) -> MLP(64->32 relu ->4)
// fp32 in/out. LSTM via split-bf16 MFMA (3-term, ~fp32 accuracy).
//
// Round 13: occupancy attack — 4 waves/SIMD via 1-tile-per-wave sharding.
//   8 single-layer dispatches (R1 dataflow), grid 256 x 1024 threads, M=8.
//   16 waves/block: wave wv owns gate-tile (gt=wv&3, jr=wv>>2) -> 12 MFMAs/step
//   (KT=4; 9 for layer 0). Per-SIMD matrix work unchanged (4 waves x 12), but
//   4 independent streams/SIMD hide ds_read->MFMA + transcendental latencies
//   (the ~1100 cy/step residue R9-R12 could not remove with 2 waves/SIMD).
//   Gate exchange via bank-tuned LDS gsw (strides 552/136/17: all reads/writes
//   <=2-way = free). Phase C: threads 0-511 = 1 cell each (c in register);
//   threads 512-1023 stage x(t+1) concurrently (pipe diversity).
//   2 __syncthreads/step. h chained between dispatches as packed (hi|lo) u32,
//   in-place in one buffer (read t+2 always 2 steps ahead of write t).
//   Float ops bit-identical to verified R1/R9-R12 -> absmax 0.0 expected.

#define BATCH 2048
#define TT 64
#define HH 64
#define LDP 136   // panel row stride in shorts (2-way-free b128 reads)
#define GJR 552   // gsw jr-block stride in floats (mod 32 = 8 -> 2-way-free)

typedef short bf16x8 __attribute__((ext_vector_type(8)));
typedef float f32x4 __attribute__((ext_vector_type(4)));

__device__ __forceinline__ float sigmoid_fast(float x) {
    return __builtin_amdgcn_rcpf(1.f + __expf(-x));
}
__device__ __forceinline__ float tanh_fast(float x) {
    float e = __expf(-2.f * x);
    e = fminf(e, 1e30f);          // keep 1+e finite so rcp>0: tanh(-big) -> -1, not NaN
    return (1.f - e) * __builtin_amdgcn_rcpf(1.f + e);
}
__device__ __forceinline__ void split2(float x, unsigned short& hi, unsigned short& lo) {
    const unsigned u = __float_as_uint(x);
    hi = (unsigned short)(u >> 16);
    const float r = x - __uint_as_float(u & 0xFFFF0000u);  // exact
    lo = (unsigned short)(__float_as_uint(r) >> 16);
}

// ---------------- input MLP: 2 -> 16 relu -> 16 ----------------
__global__ __launch_bounds__(256)
void mlp_in_kernel(const float* __restrict__ x,
                   const float* __restrict__ w1, const float* __restrict__ b1,
                   const float* __restrict__ w2, const float* __restrict__ b2,
                   float* __restrict__ out) {
    const int gid = blockIdx.x * 256 + threadIdx.x;
    const float x0 = x[gid * 2 + 0];
    const float x1 = x[gid * 2 + 1];
    float hid[16];
#pragma unroll
    for (int j = 0; j < 16; ++j) {
        float v = fmaf(x1, w1[j * 2 + 1], fmaf(x0, w1[j * 2 + 0], b1[j]));
        hid[j] = fmaxf(0.f, v);
    }
    float o[16];
#pragma unroll
    for (int oo = 0; oo < 16; ++oo) {
        float acc = b2[oo];
#pragma unroll
        for (int j = 0; j < 16; ++j) acc = fmaf(hid[j], w2[oo * 16 + j], acc);
        o[oo] = acc;
    }
    float4* op = (float4*)(out + gid * 16);
#pragma unroll
    for (int q = 0; q < 4; ++q) {
        float4 v;
        v.x = o[q * 4 + 0]; v.y = o[q * 4 + 1]; v.z = o[q * 4 + 2]; v.w = o[q * 4 + 3];
        op[q] = v;
    }
}

// ---------------- LSTM layer, 1024 threads, 16 waves, 1 tile/wave ----------------
// I = real input width; IPAD = padded x-region; K = IPAD + 64.
template <int I, int IPAD>
__global__ __launch_bounds__(1024)
void lstm_layer1k(const float* __restrict__ xf,  // layer-0 input (fp32) iff I==16
                  const unsigned* xp,            // packed h input (I==64); aliases Pout
                  unsigned* Pout,                // packed h output (if !last)
                  float* __restrict__ houtf,     // fp32 h output (if last)
                  const int last,
                  const float* __restrict__ wih, const float* __restrict__ whh,
                  const float* __restrict__ bi, const float* __restrict__ bh) {
    constexpr int KT = (IPAD + 64) / 32;
    __shared__ __align__(16) unsigned short ph[2][16 * LDP], pl[2][16 * LDP];
    __shared__ float gsw[4 * GJR];   // [jr] blocks; inside: (gt*8+row)*17 + l

    const int tid = threadIdx.x;
    const int wv = tid >> 6, lane = tid & 63, l16 = lane & 15, quad = lane >> 4;
    const int gt = wv & 3, jr = wv >> 2;
    const int base = blockIdx.x * 8;

    for (int e = tid; e < 2 * 16 * LDP; e += 1024) { (&ph[0][0])[e] = 0; (&pl[0][0])[e] = 0; }

    // --- weight B-fragments: wave's tile = gate gt, j in [16jr, 16jr+16) ---
    const int n = gt * 64 + jr * 16 + l16;
    const float bsum = bi[n] + bh[n];
    bf16x8 bhi[KT], blo[KT];
#pragma unroll
    for (int kt = 0; kt < KT; ++kt) {
#pragma unroll
        for (int j = 0; j < 8; ++j) {
            const int k = kt * 32 + quad * 8 + j;
            float w = 0.f;
            if (k < I) w = wih[n * I + k];
            else if (k >= IPAD) w = whh[n * 64 + (k - IPAD)];
            unsigned short h_, l_;
            split2(w, h_, l_);
            bhi[kt][j] = (short)h_;
            blo[kt][j] = (short)l_;
        }
    }

    // phase-C cell (threads 0-511): row = tid>>6, j = tid&63; c in one VGPR
    const int crow = tid >> 6, cj = tid & 63;
    float c = 0.f;

    // staging (threads 512+): x(t+1) -> next panel; register prefetch distance 2
    const int sidx = tid - 512;
    const bool stg = (I == 16) ? (tid >= 512 && tid < 640) : (tid >= 512);
    const int sr = (I == 16) ? (sidx >> 4) : (sidx >> 6);
    const int sc = (I == 16) ? (sidx & 15) : (sidx & 63);
    float xrf = 0.f;
    unsigned xru = 0u;
    if (stg) {
        if (I == 16) {
            xrf = xf[((size_t)(base + sr) * TT + 0) * 16 + sc];
            unsigned short h_, l_;
            split2(xrf, h_, l_);
            ph[0][sr * LDP + sc] = h_;
            pl[0][sr * LDP + sc] = l_;
            xrf = xf[((size_t)(base + sr) * TT + 1) * 16 + sc];
        } else {
            xru = xp[((size_t)(base + sr) * TT + 0) * 64 + sc];
            ph[0][sr * LDP + sc] = (unsigned short)(xru >> 16);
            pl[0][sr * LDP + sc] = (unsigned short)(xru & 0xffffu);
            xru = xp[((size_t)(base + sr) * TT + 1) * 64 + sc];
        }
    }
    __syncthreads();

    for (int t = 0; t < TT; ++t) {
        const int pb = t & 1;

        // ---- MFMA: gates(tile) = bias + [x|h] @ W^T (3-term split-bf16) ----
        f32x4 a0, a1, a2;
        a0[0] = bsum; a0[1] = bsum; a0[2] = bsum; a0[3] = bsum;
        a1 = (f32x4){0.f, 0.f, 0.f, 0.f};
        a2 = (f32x4){0.f, 0.f, 0.f, 0.f};
#pragma unroll
        for (int kt = 0; kt < KT; ++kt) {
            const int aoff = l16 * LDP + kt * 32 + quad * 8;
            const bf16x8 ahi = *(const bf16x8*)&ph[pb][aoff];
            const bf16x8 alo = *(const bf16x8*)&pl[pb][aoff];
            a0 = __builtin_amdgcn_mfma_f32_16x16x32_bf16(ahi, bhi[kt], a0, 0, 0, 0);
            a1 = __builtin_amdgcn_mfma_f32_16x16x32_bf16(alo, bhi[kt], a1, 0, 0, 0);
            a2 = __builtin_amdgcn_mfma_f32_16x16x32_bf16(ahi, blo[kt], a2, 0, 0, 0);
        }
        const f32x4 s4 = (a0 + a1) + a2;
        // D: row = quad*4+r (rows 0..7 real), col = l16. Write gates to gsw.
        if (quad < 2) {
            const int gb = jr * GJR + (gt * 8 + quad * 4) * 17 + l16;
            gsw[gb + 0]  = s4[0];
            gsw[gb + 17] = s4[1];
            gsw[gb + 34] = s4[2];
            gsw[gb + 51] = s4[3];
        }
        __syncthreads();  // gsw ready; also: all panel[pb] reads done

        // ---- phase C (threads 0-511): one cell each ----
        if (tid < 512) {
            const int gb = (cj >> 4) * GJR + crow * 17 + (cj & 15);
            const float gi = gsw[gb + 0 * 136];
            const float gf = gsw[gb + 1 * 136];
            const float gg = gsw[gb + 2 * 136];
            const float go = gsw[gb + 3 * 136];
            const float iv = sigmoid_fast(gi), fv = sigmoid_fast(gf);
            const float gv = tanh_fast(gg), ov = sigmoid_fast(go);
            c = fv * c + iv * gv;
            const float h = ov * tanh_fast(c);
            unsigned short h_, l_;
            split2(h, h_, l_);
            ph[pb ^ 1][crow * LDP + IPAD + cj] = h_;
            pl[pb ^ 1][crow * LDP + IPAD + cj] = l_;
            if (!last) {
                Pout[((size_t)(base + crow) * TT + t) * 64 + cj] =
                    ((unsigned)h_ << 16) | (unsigned)l_;
            } else {
                houtf[((size_t)(base + crow) * TT + t) * HH + cj] = h;
            }
        }

        // ---- staging (threads 512+): x(t+1) -> panel[pb^1]; prefetch x(t+2) ----
        if (stg) {
            if (I == 16) {
                unsigned short h_, l_;
                split2(xrf, h_, l_);
                ph[pb ^ 1][sr * LDP + sc] = h_;
                pl[pb ^ 1][sr * LDP + sc] = l_;
                const int tp = (t + 2) & (TT - 1);
                xrf = xf[((size_t)(base + sr) * TT + tp) * 16 + sc];
            } else {
                ph[pb ^ 1][sr * LDP + sc] = (unsigned short)(xru >> 16);
                pl[pb ^ 1][sr * LDP + sc] = (unsigned short)(xru & 0xffffu);
                const int tp = (t + 2) & (TT - 1);
                xru = xp[((size_t)(base + sr) * TT + tp) * 64 + sc];
            }
        }
        __syncthreads();  // panel[pb^1] complete (h + x staged)
    }
}

// ---------------- output MLP: 64 -> 32 relu -> 4 ----------------
__global__ __launch_bounds__(256)
void mlp_out_kernel(const float* __restrict__ hin,
                    const float* __restrict__ wo1, const float* __restrict__ bo1,
                    const float* __restrict__ wo2, const float* __restrict__ bo2,
                    float* __restrict__ out) {
    __shared__ __align__(16) float wo1_s[32 * 64];
    __shared__ float bo1_s[32];
    __shared__ float wo2_s[4 * 32];
    __shared__ float bo2_s[4];
    const int tid = threadIdx.x;
    for (int e = tid; e < 32 * 64; e += 256) wo1_s[e] = wo1[e];
    if (tid < 32) bo1_s[tid] = bo1[tid];
    if (tid < 128) wo2_s[tid] = wo2[tid];
    if (tid < 4) bo2_s[tid] = bo2[tid];
    __syncthreads();

    const int gid = blockIdx.x * 256 + tid;
    const float4* hv = (const float4*)(hin + gid * 64);
    float4 h[16];
#pragma unroll
    for (int q = 0; q < 16; ++q) h[q] = hv[q];

    float m1[32];
#pragma unroll
    for (int o = 0; o < 32; ++o) {
        float acc = bo1_s[o];
        const float4* wrow = (const float4*)(wo1_s + o * 64);
#pragma unroll
        for (int q = 0; q < 16; ++q) {
            const float4 w = wrow[q];
            acc = fmaf(h[q].x, w.x, acc);
            acc = fmaf(h[q].y, w.y, acc);
            acc = fmaf(h[q].z, w.z, acc);
            acc = fmaf(h[q].w, w.w, acc);
        }
        m1[o] = fmaxf(0.f, acc);
    }
    float r[4];
#pragma unroll
    for (int q = 0; q < 4; ++q) {
        float acc = bo2_s[q];
#pragma unroll
        for (int o = 0; o < 32; ++o) acc = fmaf(m1[o], wo2_s[q * 32 + o], acc);
        r[q] = acc;
    }
    float4 res;
    res.x = r[0]; res.y = r[1]; res.z = r[2]; res.w = r[3];
    ((float4*)out)[gid] = res;
}

extern "C" void kernel_launch(void* const* d_in, const int* in_sizes, int n_in,
                              void* d_out, int out_size, void* d_ws, size_t ws_size,
                              hipStream_t stream) {
    const float* x     = (const float*)d_in[0];
    const float* w1    = (const float*)d_in[1];
    const float* b1    = (const float*)d_in[2];
    const float* w2    = (const float*)d_in[3];
    const float* b2    = (const float*)d_in[4];
    const float* w_ih0 = (const float*)d_in[5];
    const float* w_hh0 = (const float*)d_in[6];
    const float* b_ih0 = (const float*)d_in[7];
    const float* b_hh0 = (const float*)d_in[8];
    const float* w_ih  = (const float*)d_in[9];
    const float* w_hh  = (const float*)d_in[10];
    const float* b_ih  = (const float*)d_in[11];
    const float* b_hh  = (const float*)d_in[12];
    const float* wo1   = (const float*)d_in[13];
    const float* bo1   = (const float*)d_in[14];
    const float* wo2   = (const float*)d_in[15];
    const float* bo2   = (const float*)d_in[16];

    // workspace: buf_mlp B*T*16 f32 (8 MB) | P B*T*64 u32 packed (32 MB) | bufH B*T*64 f32 (32 MB)
    // P is used in-place by layers 1..7: reads (t+2 prefetch) always precede writes (t)
    // for the same slot within a block; across dispatches stream order serializes.
    float* buf_mlp = (float*)d_ws;
    unsigned* P = (unsigned*)(buf_mlp + (size_t)BATCH * TT * 16);
    float* bufH = (float*)(P + (size_t)BATCH * TT * 64);

    const int nbt_blocks = (BATCH * TT) / 256;  // 512

    mlp_in_kernel<<<nbt_blocks, 256, 0, stream>>>(x, w1, b1, w2, b2, buf_mlp);

    // layer 0: fp32 MLP output in, packed out
    lstm_layer1k<16, 32><<<BATCH / 8, 1024, 0, stream>>>(
        buf_mlp, nullptr, P, bufH, 0, w_ih0, w_hh0, b_ih0, b_hh0);

    // layers 1..7: packed in (in-place), packed out; layer 7 writes fp32 bufH
    for (int l = 1; l < 8; ++l) {
        lstm_layer1k<64, 64><<<BATCH / 8, 1024, 0, stream>>>(
            buf_mlp, P, P, bufH, (l == 7) ? 1 : 0,
            w_ih + (size_t)(l - 1) * 256 * 64, w_hh + (size_t)(l - 1) * 256 * 64,
            b_ih + (l - 1) * 256, b_hh + (l - 1) * 256);
    }

    mlp_out_kernel<<<nbt_blocks, 256, 0, stream>>>(bufH, wo1, bo1, wo2, bo2, (float*)d_out);
}

// Round 10
// 608.734 us; speedup vs baseline: 1.0587x; 1.0587x over previous
//
#include <hip/hip_runtime.h>

// x[2048,64,2] -> MLP(2->16 relu ->16) -> 8x LSTM(H=64) -> MLP(64->32 relu ->4)
// fp32 in/out. LSTM via split-bf16 MFMA (3-term, ~fp32 accuracy).
//
// Round 14: M=16 — all 16 MFMA rows real (rows 8-15 = second batch slice).
//   4 dispatches, each fuses layers (2p, 2p+1). grid 128 x 512 threads.
//   Same R12 protocol: waves 0-3 (A) / 4-7 (B), LDS counters cA/cB/cBm,
//   4-deep h_A ring (3-step elastic slack), parity pA (x) and pHB (h_B).
//   NEW vs R12: base = 16 rows/block -> every MFMA row real (2x rows per
//   step at the same MFMA/sync/VALU overhead); phase C is 4 cells IN-PLACE
//   per lane (D rows quad*4+rr all real) -> bpermute+cndmask eliminated.
//   MFMA inputs/order and cell math bit-identical to verified R12 -> absmax 0.0.

#define BATCH 2048
#define TT 64
#define HH 64
#define RS 72     // h-panel row stride in shorts (64 cols + 8 pad)

typedef short bf16x8 __attribute__((ext_vector_type(8)));
typedef float f32x4 __attribute__((ext_vector_type(4)));
typedef unsigned short u16x4 __attribute__((ext_vector_type(4)));

__device__ __forceinline__ float sigmoid_fast(float x) {
    return __builtin_amdgcn_rcpf(1.f + __expf(-x));
}
__device__ __forceinline__ float tanh_fast(float x) {
    float e = __expf(-2.f * x);
    e = fminf(e, 1e30f);          // keep 1+e finite so rcp>0: tanh(-big) -> -1, not NaN
    return (1.f - e) * __builtin_amdgcn_rcpf(1.f + e);
}
__device__ __forceinline__ void split2(float x, unsigned short& hi, unsigned short& lo) {
    const unsigned u = __float_as_uint(x);
    hi = (unsigned short)(u >> 16);
    const float r = x - __uint_as_float(u & 0xFFFF0000u);  // exact
    lo = (unsigned short)(__float_as_uint(r) >> 16);
}
__device__ __forceinline__ void wg_wait(int* c, int v) {
    while (__hip_atomic_load(c, __ATOMIC_ACQUIRE, __HIP_MEMORY_SCOPE_WORKGROUP) < v) {}
}
__device__ __forceinline__ void wg_bump(int* c, int lane) {
    if (lane == 0)
        __hip_atomic_fetch_add(c, 1, __ATOMIC_RELEASE, __HIP_MEMORY_SCOPE_WORKGROUP);
}

// ---------------- input MLP: 2 -> 16 relu -> 16 ----------------
__global__ __launch_bounds__(256)
void mlp_in_kernel(const float* __restrict__ x,
                   const float* __restrict__ w1, const float* __restrict__ b1,
                   const float* __restrict__ w2, const float* __restrict__ b2,
                   float* __restrict__ out) {
    const int gid = blockIdx.x * 256 + threadIdx.x;
    const float x0 = x[gid * 2 + 0];
    const float x1 = x[gid * 2 + 1];
    float hid[16];
#pragma unroll
    for (int j = 0; j < 16; ++j) {
        float v = fmaf(x1, w1[j * 2 + 1], fmaf(x0, w1[j * 2 + 0], b1[j]));
        hid[j] = fmaxf(0.f, v);
    }
    float o[16];
#pragma unroll
    for (int oo = 0; oo < 16; ++oo) {
        float acc = b2[oo];
#pragma unroll
        for (int j = 0; j < 16; ++j) acc = fmaf(hid[j], w2[oo * 16 + j], acc);
        o[oo] = acc;
    }
    float4* op = (float4*)(out + gid * 16);
#pragma unroll
    for (int q = 0; q < 4; ++q) {
        float4 v;
        v.x = o[q * 4 + 0]; v.y = o[q * 4 + 1]; v.z = o[q * 4 + 2]; v.w = o[q * 4 + 3];
        op[q] = v;
    }
}

// ---------------- fused LSTM layer pair, M=16, ring handoff, 512 threads ----------------
// K layout (A): k in [0,IPADA) = x (pA); k in [IPADA,IPADA+64) = h_A (ring slot t-1).
// K layout (B): k in [0,64) = h_A (ring slot t); k in [64,128) = h_B (pHB).
template <int IA, int IPADA>
__global__ __launch_bounds__(512, 2)
void lstm_pair(const float* __restrict__ xmlp,   // A input iff IA==16
               unsigned* __restrict__ P,          // packed h buffer (A in / B out)
               float* __restrict__ houtf,         // B out iff last
               const int last,
               const float* __restrict__ wihA, const float* __restrict__ whhA,
               const float* __restrict__ biA, const float* __restrict__ bhA,
               const float* __restrict__ wihB, const float* __restrict__ whhB,
               const float* __restrict__ biB, const float* __restrict__ bhB) {
    constexpr int KTA = (IPADA + 64) / 32;  // total k-tiles for A
    constexpr int KTX = IPADA / 32;         // k-tiles living in pA (x region)
    constexpr int LDPA = IPADA + 8;         // pA row stride (shorts)
    __shared__ __align__(16) unsigned short pAh[2][16 * LDPA], pAl[2][16 * LDPA];
    __shared__ __align__(16) unsigned short rHh[4][16 * RS], rHl[4][16 * RS];  // h_A ring
    __shared__ __align__(16) unsigned short pHh[2][16 * RS], pHl[2][16 * RS];  // h_B parity
    __shared__ int cA, cB, cBm;

    const int tid = threadIdx.x;
    const int wv = tid >> 6, lane = tid & 63, l16 = lane & 15, quad = lane >> 4;
    const int grp = wv >> 2;   // 0 = layer A, 1 = layer B
    const int wg = wv & 3;     // j-group within layer
    const int base = blockIdx.x * 16;   // 16 batch rows per block (all MFMA rows real)

    if (tid == 0) { cA = 0; cB = 0; cBm = 0; }
    for (int e = tid; e < 2 * 16 * LDPA; e += 512) { (&pAh[0][0])[e] = 0; (&pAl[0][0])[e] = 0; }
    for (int e = tid; e < 4 * 16 * RS; e += 512)   { (&rHh[0][0])[e] = 0; (&rHl[0][0])[e] = 0; }
    for (int e = tid; e < 2 * 16 * RS; e += 512)   { (&pHh[0][0])[e] = 0; (&pHl[0][0])[e] = 0; }

    // per-wave layer params (wave-uniform)
    const int I    = grp ? 64 : IA;
    const int IPAD = grp ? 64 : IPADA;
    const int KT   = grp ? 4  : KTA;
    const float* wih = grp ? wihB : wihA;
    const float* whh = grp ? whhB : whhA;
    const float* bi  = grp ? biB  : biA;
    const float* bh  = grp ? bhB  : bhA;

    // --- weight B-fragments, gate-per-tile: tile gt = gate gt for j in [16wg,16wg+16) ---
    const int jg = 16 * wg + l16;
    bf16x8 bhi[4][4], blo[4][4];  // [kt][gt]
    float bsum[4];
#pragma unroll
    for (int gt = 0; gt < 4; ++gt) {
        const int n = gt * 64 + jg;
        bsum[gt] = bi[n] + bh[n];
#pragma unroll
        for (int kt = 0; kt < 4; ++kt) {
            bf16x8 vh = {0, 0, 0, 0, 0, 0, 0, 0};
            bf16x8 vl = {0, 0, 0, 0, 0, 0, 0, 0};
            if (kt < KT) {
#pragma unroll
                for (int j = 0; j < 8; ++j) {
                    const int k = kt * 32 + quad * 8 + j;
                    float w = 0.f;
                    if (k < I) w = wih[n * I + k];
                    else if (k >= IPAD) w = whh[n * 64 + (k - IPAD)];
                    unsigned short h_, l_;
                    split2(w, h_, l_);
                    vh[j] = (short)h_;
                    vl[j] = (short)l_;
                }
            }
            bhi[kt][gt] = vh;
            blo[kt][gt] = vl;
        }
    }

    // c-state: 4 cells/lane, rows quad*4+rr (ALL real), col jg
    float cs[4] = {0.f, 0.f, 0.f, 0.f};

    // --- staging setup (A-group, 256 threads = 16 rows): x(0) -> pA[0]; prefetch x(1) ---
    float xrf = 0.f;
    uint4 xr4 = {0u, 0u, 0u, 0u};
    const int sr = tid >> 4;            // 0..15
    const int scf = tid & 15;           // IA==16: one f32 col
    const int sc4 = (tid & 15) * 4;     // IA==64: four packed u32 cols
    if (grp == 0) {
        if (IA == 16) {
            xrf = xmlp[((size_t)(base + sr) * TT + 0) * 16 + scf];
            unsigned short h_, l_;
            split2(xrf, h_, l_);
            pAh[0][sr * LDPA + scf] = h_;
            pAl[0][sr * LDPA + scf] = l_;
            xrf = xmlp[((size_t)(base + sr) * TT + 1) * 16 + scf];
        } else {
            xr4 = *(const uint4*)&P[((size_t)(base + sr) * TT + 0) * 64 + sc4];
            u16x4 hv, lv;
            hv[0] = (unsigned short)(xr4.x >> 16); lv[0] = (unsigned short)(xr4.x & 0xffffu);
            hv[1] = (unsigned short)(xr4.y >> 16); lv[1] = (unsigned short)(xr4.y & 0xffffu);
            hv[2] = (unsigned short)(xr4.z >> 16); lv[2] = (unsigned short)(xr4.z & 0xffffu);
            hv[3] = (unsigned short)(xr4.w >> 16); lv[3] = (unsigned short)(xr4.w & 0xffffu);
            *(u16x4*)&pAh[0][sr * LDPA + sc4] = hv;
            *(u16x4*)&pAl[0][sr * LDPA + sc4] = lv;
            xr4 = *(const uint4*)&P[((size_t)(base + sr) * TT + 1) * 64 + sc4];
        }
    }
    __syncthreads();   // panels + counters ready; last barrier in the kernel

    if (grp == 0) {
        // ================= group A: layer A, steps 0..63 =================
        for (int t = 0; t < TT; ++t) {
            const int pb = t & 1;
            const int rsl = t & 3;          // ring slot to write (h_A(t))
            const int rpr = (t + 3) & 3;    // ring slot to read (h_A(t-1))
            if (t) wg_wait(&cA, 4 * t);     // own group: h_A(t-1) + staging complete
            // ---- stage x(t+1) into pA[pb^1] ----
            if (IA == 16) {
                unsigned short h_, l_;
                split2(xrf, h_, l_);
                pAh[pb ^ 1][sr * LDPA + scf] = h_;
                pAl[pb ^ 1][sr * LDPA + scf] = l_;
                const int tp = (t + 2) & (TT - 1);
                xrf = xmlp[((size_t)(base + sr) * TT + tp) * 16 + scf];
            } else {
                u16x4 hv, lv;
                hv[0] = (unsigned short)(xr4.x >> 16); lv[0] = (unsigned short)(xr4.x & 0xffffu);
                hv[1] = (unsigned short)(xr4.y >> 16); lv[1] = (unsigned short)(xr4.y & 0xffffu);
                hv[2] = (unsigned short)(xr4.z >> 16); lv[2] = (unsigned short)(xr4.z & 0xffffu);
                hv[3] = (unsigned short)(xr4.w >> 16); lv[3] = (unsigned short)(xr4.w & 0xffffu);
                *(u16x4*)&pAh[pb ^ 1][sr * LDPA + sc4] = hv;
                *(u16x4*)&pAl[pb ^ 1][sr * LDPA + sc4] = lv;
                const int tp = (t + 2) & (TT - 1);
                xr4 = *(const uint4*)&P[((size_t)(base + sr) * TT + tp) * 64 + sc4];
            }
            // ---- preload A-fragments: x from pA[pb], h_A(t-1) from ring slot rpr ----
            bf16x8 ahi[4], alo[4];
#pragma unroll
            for (int kt = 0; kt < KTA; ++kt) {
                if (kt < KTX) {
                    const int aoff = l16 * LDPA + kt * 32 + quad * 8;
                    ahi[kt] = *(const bf16x8*)&pAh[pb][aoff];
                    alo[kt] = *(const bf16x8*)&pAl[pb][aoff];
                } else {
                    const int aoff = l16 * RS + (kt - KTX) * 32 + quad * 8;
                    ahi[kt] = *(const bf16x8*)&rHh[rpr][aoff];
                    alo[kt] = *(const bf16x8*)&rHl[rpr][aoff];
                }
            }
            f32x4 a0[4], a1[4], a2[4];
#pragma unroll
            for (int gt = 0; gt < 4; ++gt) {
                a0[gt][0] = bsum[gt]; a0[gt][1] = bsum[gt];
                a0[gt][2] = bsum[gt]; a0[gt][3] = bsum[gt];
                a1[gt] = (f32x4){0.f, 0.f, 0.f, 0.f};
                a2[gt] = (f32x4){0.f, 0.f, 0.f, 0.f};
            }
            __builtin_amdgcn_s_setprio(1);
#pragma unroll
            for (int kt = 0; kt < KTA; ++kt) {
#pragma unroll
                for (int gt = 0; gt < 4; ++gt) {
                    a0[gt] = __builtin_amdgcn_mfma_f32_16x16x32_bf16(ahi[kt], bhi[kt][gt], a0[gt], 0, 0, 0);
                    a1[gt] = __builtin_amdgcn_mfma_f32_16x16x32_bf16(alo[kt], bhi[kt][gt], a1[gt], 0, 0, 0);
                    a2[gt] = __builtin_amdgcn_mfma_f32_16x16x32_bf16(ahi[kt], blo[kt][gt], a2[gt], 0, 0, 0);
                }
            }
            __builtin_amdgcn_s_setprio(0);
            // sums (exact verified order); 4 cells IN-PLACE per lane (rows all real)
            f32x4 s4[4];
#pragma unroll
            for (int gt = 0; gt < 4; ++gt) s4[gt] = (a0[gt] + a1[gt]) + a2[gt];
            float hv4[4];
#pragma unroll
            for (int rr = 0; rr < 4; ++rr) {
                const float iv = sigmoid_fast(s4[0][rr]);
                const float fv = sigmoid_fast(s4[1][rr]);
                const float gv = tanh_fast(s4[2][rr]);
                const float ov = sigmoid_fast(s4[3][rr]);
                const float cn = fv * cs[rr] + iv * gv;
                cs[rr] = cn;
                hv4[rr] = ov * tanh_fast(cn);
            }
            // ---- overwrite gate: B@(t-4) must have preloaded ring slot rsl ----
            if (t >= 4) wg_wait(&cBm, 4 * (t - 3));
#pragma unroll
            for (int rr = 0; rr < 4; ++rr) {
                const int R = quad * 4 + rr;
                unsigned short h_, l_;
                split2(hv4[rr], h_, l_);
                rHh[rsl][R * RS + jg] = h_;   // h_A(t) -> ring slot t&3
                rHl[rsl][R * RS + jg] = l_;
            }
            wg_bump(&cA, lane);
        }
    } else {
        // ================= group B: layer B, steps 0..63 =================
        for (int t = 0; t < TT; ++t) {
            const int pb = t & 1;
            const int rsl = t & 3;          // ring slot holding h_A(t)
            if (t) wg_wait(&cB, 4 * t);
            wg_wait(&cA, 4 * (t + 1));      // h_A(t) complete (pre-satisfied when lagging)
            // ---- preload: h_A(t) from ring, h_B(t-1) from pHB[(t-1)&1] ----
            bf16x8 ahi[4], alo[4];
#pragma unroll
            for (int kt = 0; kt < 2; ++kt) {
                const int aoff = l16 * RS + kt * 32 + quad * 8;
                ahi[kt] = *(const bf16x8*)&rHh[rsl][aoff];
                alo[kt] = *(const bf16x8*)&rHl[rsl][aoff];
            }
#pragma unroll
            for (int kt = 2; kt < 4; ++kt) {
                const int aoff = l16 * RS + (kt - 2) * 32 + quad * 8;
                ahi[kt] = *(const bf16x8*)&pHh[pb ^ 1][aoff];
                alo[kt] = *(const bf16x8*)&pHl[pb ^ 1][aoff];
            }
            wg_bump(&cBm, lane);   // release: A may overwrite ring slot rsl (at t+4)
            f32x4 a0[4], a1[4], a2[4];
#pragma unroll
            for (int gt = 0; gt < 4; ++gt) {
                a0[gt][0] = bsum[gt]; a0[gt][1] = bsum[gt];
                a0[gt][2] = bsum[gt]; a0[gt][3] = bsum[gt];
                a1[gt] = (f32x4){0.f, 0.f, 0.f, 0.f};
                a2[gt] = (f32x4){0.f, 0.f, 0.f, 0.f};
            }
            __builtin_amdgcn_s_setprio(1);
#pragma unroll
            for (int kt = 0; kt < 4; ++kt) {
#pragma unroll
                for (int gt = 0; gt < 4; ++gt) {
                    a0[gt] = __builtin_amdgcn_mfma_f32_16x16x32_bf16(ahi[kt], bhi[kt][gt], a0[gt], 0, 0, 0);
                    a1[gt] = __builtin_amdgcn_mfma_f32_16x16x32_bf16(alo[kt], bhi[kt][gt], a1[gt], 0, 0, 0);
                    a2[gt] = __builtin_amdgcn_mfma_f32_16x16x32_bf16(ahi[kt], blo[kt][gt], a2[gt], 0, 0, 0);
                }
            }
            __builtin_amdgcn_s_setprio(0);
            f32x4 s4[4];
#pragma unroll
            for (int gt = 0; gt < 4; ++gt) s4[gt] = (a0[gt] + a1[gt]) + a2[gt];
#pragma unroll
            for (int rr = 0; rr < 4; ++rr) {
                const float iv = sigmoid_fast(s4[0][rr]);
                const float fv = sigmoid_fast(s4[1][rr]);
                const float gv = tanh_fast(s4[2][rr]);
                const float ov = sigmoid_fast(s4[3][rr]);
                const float cn = fv * cs[rr] + iv * gv;
                cs[rr] = cn;
                const float h = ov * tanh_fast(cn);
                const int R = quad * 4 + rr;
                unsigned short h_, l_;
                split2(h, h_, l_);
                pHh[pb][R * RS + jg] = h_;   // h_B(t) recurrence
                pHl[pb][R * RS + jg] = l_;
                if (!last) {
                    P[((size_t)(base + R) * TT + t) * 64 + jg] =
                        ((unsigned)h_ << 16) | (unsigned)l_;
                } else {
                    houtf[((size_t)(base + R) * TT + t) * HH + jg] = h;
                }
            }
            wg_bump(&cB, lane);
        }
    }
}

// ---------------- output MLP: 64 -> 32 relu -> 4 ----------------
__global__ __launch_bounds__(256)
void mlp_out_kernel(const float* __restrict__ hin,
                    const float* __restrict__ wo1, const float* __restrict__ bo1,
                    const float* __restrict__ wo2, const float* __restrict__ bo2,
                    float* __restrict__ out) {
    __shared__ __align__(16) float wo1_s[32 * 64];
    __shared__ float bo1_s[32];
    __shared__ float wo2_s[4 * 32];
    __shared__ float bo2_s[4];
    const int tid = threadIdx.x;
    for (int e = tid; e < 32 * 64; e += 256) wo1_s[e] = wo1[e];
    if (tid < 32) bo1_s[tid] = bo1[tid];
    if (tid < 128) wo2_s[tid] = wo2[tid];
    if (tid < 4) bo2_s[tid] = bo2[tid];
    __syncthreads();

    const int gid = blockIdx.x * 256 + tid;
    const float4* hv = (const float4*)(hin + gid * 64);
    float4 h[16];
#pragma unroll
    for (int q = 0; q < 16; ++q) h[q] = hv[q];

    float m1[32];
#pragma unroll
    for (int o = 0; o < 32; ++o) {
        float acc = bo1_s[o];
        const float4* wrow = (const float4*)(wo1_s + o * 64);
#pragma unroll
        for (int q = 0; q < 16; ++q) {
            const float4 w = wrow[q];
            acc = fmaf(h[q].x, w.x, acc);
            acc = fmaf(h[q].y, w.y, acc);
            acc = fmaf(h[q].z, w.z, acc);
            acc = fmaf(h[q].w, w.w, acc);
        }
        m1[o] = fmaxf(0.f, acc);
    }
    float r[4];
#pragma unroll
    for (int q = 0; q < 4; ++q) {
        float acc = bo2_s[q];
#pragma unroll
        for (int o = 0; o < 32; ++o) acc = fmaf(m1[o], wo2_s[q * 32 + o], acc);
        r[q] = acc;
    }
    float4 res;
    res.x = r[0]; res.y = r[1]; res.z = r[2]; res.w = r[3];
    ((float4*)out)[gid] = res;
}

extern "C" void kernel_launch(void* const* d_in, const int* in_sizes, int n_in,
                              void* d_out, int out_size, void* d_ws, size_t ws_size,
                              hipStream_t stream) {
    const float* x     = (const float*)d_in[0];
    const float* w1    = (const float*)d_in[1];
    const float* b1    = (const float*)d_in[2];
    const float* w2    = (const float*)d_in[3];
    const float* b2    = (const float*)d_in[4];
    const float* w_ih0 = (const float*)d_in[5];
    const float* w_hh0 = (const float*)d_in[6];
    const float* b_ih0 = (const float*)d_in[7];
    const float* b_hh0 = (const float*)d_in[8];
    const float* w_ih  = (const float*)d_in[9];
    const float* w_hh  = (const float*)d_in[10];
    const float* b_ih  = (const float*)d_in[11];
    const float* b_hh  = (const float*)d_in[12];
    const float* wo1   = (const float*)d_in[13];
    const float* bo1   = (const float*)d_in[14];
    const float* wo2   = (const float*)d_in[15];
    const float* bo2   = (const float*)d_in[16];

    // workspace: buf_mlp B*T*16 f32 (8 MB) | P B*T*64 u32 packed (32 MB) | bufH B*T*64 f32 (32 MB)
    float* buf_mlp = (float*)d_ws;
    unsigned* P = (unsigned*)(buf_mlp + (size_t)BATCH * TT * 16);
    float* bufH = (float*)(P + (size_t)BATCH * TT * 64);

    const int nbt_blocks = (BATCH * TT) / 256;  // 512

    mlp_in_kernel<<<nbt_blocks, 256, 0, stream>>>(x, w1, b1, w2, b2, buf_mlp);

    // pair 0: layers 0,1
    lstm_pair<16, 32><<<BATCH / 16, 512, 0, stream>>>(
        buf_mlp, P, bufH, 0,
        w_ih0, w_hh0, b_ih0, b_hh0,
        w_ih + (size_t)0 * 256 * 64, w_hh + (size_t)0 * 256 * 64, b_ih + 0 * 256, b_hh + 0 * 256);

    // pairs 1..3: layers (2,3), (4,5), (6,7) -> w_ih/w_hh indices (1,2), (3,4), (5,6)
    for (int p = 1; p < 4; ++p) {
        const int la = 2 * p - 1, lb = 2 * p;  // indices into w_ih/w_hh arrays (layer l -> idx l-1)
        lstm_pair<64, 64><<<BATCH / 16, 512, 0, stream>>>(
            buf_mlp, P, bufH, (p == 3) ? 1 : 0,
            w_ih + (size_t)la * 256 * 64, w_hh + (size_t)la * 256 * 64,
            b_ih + la * 256, b_hh + la * 256,
            w_ih + (size_t)lb * 256 * 64, w_hh + (size_t)lb * 256 * 64,
            b_ih + lb * 256, b_hh + lb * 256);
    }

    mlp_out_kernel<<<nbt_blocks, 256, 0, stream>>>(bufH, wo1, bo1, wo2, bo2, (float*)d_out);
}

// Round 12
// 528.058 us; speedup vs baseline: 1.2204x; 1.1528x over previous
//
#include <hip/hip_runtime.h>

// x[2048,64,2] -> MLP(2->16 relu ->16) -> 8x LSTM(H=64) -> MLP(64->32 relu ->4)
// fp32 in/out. LSTM via split-bf16 MFMA (3-term, ~fp32 accuracy).
//
// Round 15 (resubmit; R11 bench never acquired a GPU): R12 base (best: 509us)
// + x-part MFMAs hoisted OFF the recurrence chain.
//   4 dispatches, each fuses layers (2p, 2p+1). grid 256 x 512 threads, M=8.
//   Waves 0-3 (A): layer A; waves 4-7 (B): layer B, elastic 1-3 step lag.
//   pA is a 4-deep x-ring staged at distance 2 -> x(t) is ready BEFORE step t's
//   cA wait (guaranteed by step t-1's wait). A issues acc-init + x-part MFMAs
//   (kt < KTX) + x staging PRE-WAIT; only h-frag reads + h-part MFMAs + phase C
//   + ring-write remain on the recurrence critical path (~590 cy shorter).
//   B: own-h (pHB) preload moved between cB and cA waits.
//   kt accumulation order unchanged (x-kts then h-kts) -> bit-identical math.
//   Protocol (cA/cB/cBm counters, 4-deep h_A ring, parity pHB) = verified R12.

#define BATCH 2048
#define TT 64
#define HH 64
#define RS 72     // h-panel row stride in shorts (64 cols + 8 pad)

typedef short bf16x8 __attribute__((ext_vector_type(8)));
typedef float f32x4 __attribute__((ext_vector_type(4)));

__device__ __forceinline__ float sigmoid_fast(float x) {
    return __builtin_amdgcn_rcpf(1.f + __expf(-x));
}
__device__ __forceinline__ float tanh_fast(float x) {
    float e = __expf(-2.f * x);
    e = fminf(e, 1e30f);          // keep 1+e finite so rcp>0: tanh(-big) -> -1, not NaN
    return (1.f - e) * __builtin_amdgcn_rcpf(1.f + e);
}
__device__ __forceinline__ void split2(float x, unsigned short& hi, unsigned short& lo) {
    const unsigned u = __float_as_uint(x);
    hi = (unsigned short)(u >> 16);
    const float r = x - __uint_as_float(u & 0xFFFF0000u);  // exact
    lo = (unsigned short)(__float_as_uint(r) >> 16);
}
__device__ __forceinline__ void wg_wait(int* c, int v) {
    while (__hip_atomic_load(c, __ATOMIC_ACQUIRE, __HIP_MEMORY_SCOPE_WORKGROUP) < v) {}
}
__device__ __forceinline__ void wg_bump(int* c, int lane) {
    if (lane == 0)
        __hip_atomic_fetch_add(c, 1, __ATOMIC_RELEASE, __HIP_MEMORY_SCOPE_WORKGROUP);
}

// ---------------- input MLP: 2 -> 16 relu -> 16 ----------------
__global__ __launch_bounds__(256)
void mlp_in_kernel(const float* __restrict__ x,
                   const float* __restrict__ w1, const float* __restrict__ b1,
                   const float* __restrict__ w2, const float* __restrict__ b2,
                   float* __restrict__ out) {
    const int gid = blockIdx.x * 256 + threadIdx.x;
    const float x0 = x[gid * 2 + 0];
    const float x1 = x[gid * 2 + 1];
    float hid[16];
#pragma unroll
    for (int j = 0; j < 16; ++j) {
        float v = fmaf(x1, w1[j * 2 + 1], fmaf(x0, w1[j * 2 + 0], b1[j]));
        hid[j] = fmaxf(0.f, v);
    }
    float o[16];
#pragma unroll
    for (int oo = 0; oo < 16; ++oo) {
        float acc = b2[oo];
#pragma unroll
        for (int j = 0; j < 16; ++j) acc = fmaf(hid[j], w2[oo * 16 + j], acc);
        o[oo] = acc;
    }
    float4* op = (float4*)(out + gid * 16);
#pragma unroll
    for (int q = 0; q < 4; ++q) {
        float4 v;
        v.x = o[q * 4 + 0]; v.y = o[q * 4 + 1]; v.z = o[q * 4 + 2]; v.w = o[q * 4 + 3];
        op[q] = v;
    }
}

// ---------------- fused LSTM layer pair, M=8, 512 threads ----------------
// K layout (A): k in [0,IPADA) = x (pA x-ring); k in [IPADA,IPADA+64) = h_A (ring t-1).
// K layout (B): k in [0,64) = h_A (ring slot t); k in [64,128) = h_B (pHB).
template <int IA, int IPADA>
__global__ __launch_bounds__(512, 2)
void lstm_pair(const float* __restrict__ xmlp,   // A input iff IA==16
               unsigned* __restrict__ P,          // packed h buffer (A in / B out)
               float* __restrict__ houtf,         // B out iff last
               const int last,
               const float* __restrict__ wihA, const float* __restrict__ whhA,
               const float* __restrict__ biA, const float* __restrict__ bhA,
               const float* __restrict__ wihB, const float* __restrict__ whhB,
               const float* __restrict__ biB, const float* __restrict__ bhB) {
    constexpr int KTA = (IPADA + 64) / 32;  // total k-tiles for A
    constexpr int KTX = IPADA / 32;         // k-tiles living in pA (x region)
    constexpr int LDPA = IPADA + 8;         // pA row stride (shorts)
    __shared__ __align__(16) unsigned short pAh[4][16 * LDPA], pAl[4][16 * LDPA];  // x-ring
    __shared__ __align__(16) unsigned short rHh[4][16 * RS], rHl[4][16 * RS];      // h_A ring
    __shared__ __align__(16) unsigned short pHh[2][16 * RS], pHl[2][16 * RS];      // h_B parity
    __shared__ int cA, cB, cBm;

    const int tid = threadIdx.x;
    const int wv = tid >> 6, lane = tid & 63, l16 = lane & 15, quad = lane >> 4;
    const int grp = wv >> 2;   // 0 = layer A, 1 = layer B
    const int wg = wv & 3;     // j-group within layer
    const int base = blockIdx.x * 8;
    const bool lo32 = (lane < 32);
    const int bpi = (lane & 31) << 2;   // ds_bpermute byte index: partner lane-32

    if (tid == 0) { cA = 0; cB = 0; cBm = 0; }
    for (int e = tid; e < 4 * 16 * LDPA; e += 512) { (&pAh[0][0])[e] = 0; (&pAl[0][0])[e] = 0; }
    for (int e = tid; e < 4 * 16 * RS; e += 512)   { (&rHh[0][0])[e] = 0; (&rHl[0][0])[e] = 0; }
    for (int e = tid; e < 2 * 16 * RS; e += 512)   { (&pHh[0][0])[e] = 0; (&pHl[0][0])[e] = 0; }

    // per-wave layer params (wave-uniform)
    const int I    = grp ? 64 : IA;
    const int IPAD = grp ? 64 : IPADA;
    const int KT   = grp ? 4  : KTA;
    const float* wih = grp ? wihB : wihA;
    const float* whh = grp ? whhB : whhA;
    const float* bi  = grp ? biB  : biA;
    const float* bh  = grp ? bhB  : bhA;

    // --- weight B-fragments, gate-per-tile: tile gt = gate gt for j in [16wg,16wg+16) ---
    const int jg = 16 * wg + l16;
    bf16x8 bhi[4][4], blo[4][4];  // [kt][gt]
    float bsum[4];
#pragma unroll
    for (int gt = 0; gt < 4; ++gt) {
        const int n = gt * 64 + jg;
        bsum[gt] = bi[n] + bh[n];
#pragma unroll
        for (int kt = 0; kt < 4; ++kt) {
            bf16x8 vh = {0, 0, 0, 0, 0, 0, 0, 0};
            bf16x8 vl = {0, 0, 0, 0, 0, 0, 0, 0};
            if (kt < KT) {
#pragma unroll
                for (int j = 0; j < 8; ++j) {
                    const int k = kt * 32 + quad * 8 + j;
                    float w = 0.f;
                    if (k < I) w = wih[n * I + k];
                    else if (k >= IPAD) w = whh[n * 64 + (k - IPAD)];
                    unsigned short h_, l_;
                    split2(w, h_, l_);
                    vh[j] = (short)h_;
                    vl[j] = (short)l_;
                }
            }
            bhi[kt][gt] = vh;
            blo[kt][gt] = vl;
        }
    }

    // c-state: 2 cells/lane, rows row0+r, col jg
    float cs[2] = {0.f, 0.f};
    const int row0 = (quad & 1) * 4 + ((quad >> 1) << 1);

    // --- staging setup (A-group): x(0)->slot0, x(1)->slot1; prefetch x(2) ---
    float2 xr2 = {0.f, 0.f};
    uint2 xru = {0u, 0u};
    int sr = 0, sc = 0, srd = 0;
    bool stg = false;
    if (grp == 0) {
        if (IA == 16) {
            stg = (tid < 128);
            sr = tid >> 3; sc = (tid & 7) * 2;       // sr 0..15; rows 8-15 are junk pad
            srd = base + (sr & 7);                    // clamp global read row to valid range
            if (stg) {
#pragma unroll
                for (int s = 0; s < 2; ++s) {
                    xr2 = *(const float2*)&xmlp[((size_t)srd * TT + s) * 16 + sc];
                    unsigned short h0, l0, h1, l1;
                    split2(xr2.x, h0, l0); split2(xr2.y, h1, l1);
                    *(unsigned*)&pAh[s][sr * LDPA + sc] = ((unsigned)h1 << 16) | h0;
                    *(unsigned*)&pAl[s][sr * LDPA + sc] = ((unsigned)l1 << 16) | l0;
                }
                xr2 = *(const float2*)&xmlp[((size_t)srd * TT + 2) * 16 + sc];
            }
        } else {
            stg = true;
            sr = tid >> 5; sc = (tid & 31) * 2;
            srd = base + sr;
#pragma unroll
            for (int s = 0; s < 2; ++s) {
                xru = *(const uint2*)&P[((size_t)srd * TT + s) * 64 + sc];
                *(unsigned*)&pAh[s][sr * LDPA + sc] = (xru.y & 0xFFFF0000u) | (xru.x >> 16);
                *(unsigned*)&pAl[s][sr * LDPA + sc] = (xru.y << 16) | (xru.x & 0xFFFFu);
            }
            xru = *(const uint2*)&P[((size_t)srd * TT + 2) * 64 + sc];
        }
    }
    __syncthreads();   // panels + counters ready; last barrier in the kernel

    if (grp == 0) {
        // ================= group A: layer A, steps 0..63 =================
        for (int t = 0; t < TT; ++t) {
            const int xsl = t & 3;          // x-ring slot for x(t)
            const int rsl = t & 3;          // h-ring slot to write (h_A(t))
            const int rpr = (t + 3) & 3;    // h-ring slot to read (h_A(t-1))

            // ---- (a) PRE-WAIT: acc init + x-part MFMAs (x(t) staged at t-2,
            //      visibility guaranteed by step t-1's cA wait) ----
            f32x4 a0[4], a1[4], a2[4];
#pragma unroll
            for (int gt = 0; gt < 4; ++gt) {
                a0[gt][0] = bsum[gt]; a0[gt][1] = bsum[gt];
                a0[gt][2] = bsum[gt]; a0[gt][3] = bsum[gt];
                a1[gt] = (f32x4){0.f, 0.f, 0.f, 0.f};
                a2[gt] = (f32x4){0.f, 0.f, 0.f, 0.f};
            }
            {
                bf16x8 xhi[KTX], xlo[KTX];
#pragma unroll
                for (int kt = 0; kt < KTX; ++kt) {
                    const int aoff = l16 * LDPA + kt * 32 + quad * 8;
                    xhi[kt] = *(const bf16x8*)&pAh[xsl][aoff];
                    xlo[kt] = *(const bf16x8*)&pAl[xsl][aoff];
                }
                __builtin_amdgcn_s_setprio(1);
#pragma unroll
                for (int kt = 0; kt < KTX; ++kt) {
#pragma unroll
                    for (int gt = 0; gt < 4; ++gt) {
                        a0[gt] = __builtin_amdgcn_mfma_f32_16x16x32_bf16(xhi[kt], bhi[kt][gt], a0[gt], 0, 0, 0);
                        a1[gt] = __builtin_amdgcn_mfma_f32_16x16x32_bf16(xlo[kt], bhi[kt][gt], a1[gt], 0, 0, 0);
                        a2[gt] = __builtin_amdgcn_mfma_f32_16x16x32_bf16(xhi[kt], blo[kt][gt], a2[gt], 0, 0, 0);
                    }
                }
                __builtin_amdgcn_s_setprio(0);
            }
            // ---- (b) stage x(t+2) -> slot (t+2)&3; prefetch x(t+3).
            //      Safe pre-wait: readers of x(t-2) (same slot) finished at t-2,
            //      guaranteed by the cA>=4(t-1) wait we passed at step t-1. ----
            if (stg) {
                const int wsl = (t + 2) & 3;
                if (IA == 16) {
                    unsigned short h0, l0, h1, l1;
                    split2(xr2.x, h0, l0); split2(xr2.y, h1, l1);
                    *(unsigned*)&pAh[wsl][sr * LDPA + sc] = ((unsigned)h1 << 16) | h0;
                    *(unsigned*)&pAl[wsl][sr * LDPA + sc] = ((unsigned)l1 << 16) | l0;
                    const int tp = (t + 3) & (TT - 1);
                    xr2 = *(const float2*)&xmlp[((size_t)srd * TT + tp) * 16 + sc];
                } else {
                    *(unsigned*)&pAh[wsl][sr * LDPA + sc] = (xru.y & 0xFFFF0000u) | (xru.x >> 16);
                    *(unsigned*)&pAl[wsl][sr * LDPA + sc] = (xru.y << 16) | (xru.x & 0xFFFFu);
                    const int tp = (t + 3) & (TT - 1);
                    xru = *(const uint2*)&P[((size_t)srd * TT + tp) * 64 + sc];
                }
            }

            // ---- (c) WAIT + h-part: h_A(t-1) from ring slot rpr ----
            if (t) wg_wait(&cA, 4 * t);
            {
                bf16x8 hhi[KTA - KTX], hlo[KTA - KTX];
#pragma unroll
                for (int kt = KTX; kt < KTA; ++kt) {
                    const int aoff = l16 * RS + (kt - KTX) * 32 + quad * 8;
                    hhi[kt - KTX] = *(const bf16x8*)&rHh[rpr][aoff];
                    hlo[kt - KTX] = *(const bf16x8*)&rHl[rpr][aoff];
                }
                __builtin_amdgcn_s_setprio(1);
#pragma unroll
                for (int kt = KTX; kt < KTA; ++kt) {
#pragma unroll
                    for (int gt = 0; gt < 4; ++gt) {
                        a0[gt] = __builtin_amdgcn_mfma_f32_16x16x32_bf16(hhi[kt - KTX], bhi[kt][gt], a0[gt], 0, 0, 0);
                        a1[gt] = __builtin_amdgcn_mfma_f32_16x16x32_bf16(hlo[kt - KTX], bhi[kt][gt], a1[gt], 0, 0, 0);
                        a2[gt] = __builtin_amdgcn_mfma_f32_16x16x32_bf16(hhi[kt - KTX], blo[kt][gt], a2[gt], 0, 0, 0);
                    }
                }
                __builtin_amdgcn_s_setprio(0);
            }

            // ---- (d) sums (exact verified order) + full-wave redistribution ----
            f32x4 s4[4];
#pragma unroll
            for (int gt = 0; gt < 4; ++gt) s4[gt] = (a0[gt] + a1[gt]) + a2[gt];
            float gk[4][2];
#pragma unroll
            for (int gt = 0; gt < 4; ++gt) {
#pragma unroll
                for (int r = 0; r < 2; ++r) {
                    const float up = __uint_as_float(
                        __builtin_amdgcn_ds_bpermute(bpi, __float_as_uint(s4[gt][r + 2])));
                    gk[gt][r] = lo32 ? s4[gt][r] : up;
                }
            }
            float hv[2];
#pragma unroll
            for (int r = 0; r < 2; ++r) {
                const float iv = sigmoid_fast(gk[0][r]);
                const float fv = sigmoid_fast(gk[1][r]);
                const float gv = tanh_fast(gk[2][r]);
                const float ov = sigmoid_fast(gk[3][r]);
                const float cn = fv * cs[r] + iv * gv;
                cs[r] = cn;
                hv[r] = ov * tanh_fast(cn);
            }
            // ---- (e) overwrite gate: B@(t-4) must have preloaded ring slot rsl ----
            if (t >= 4) wg_wait(&cBm, 4 * (t - 3));
#pragma unroll
            for (int r = 0; r < 2; ++r) {
                const int R = row0 + r;
                unsigned short h_, l_;
                split2(hv[r], h_, l_);
                rHh[rsl][R * RS + jg] = h_;   // h_A(t) -> ring slot t&3
                rHl[rsl][R * RS + jg] = l_;
            }
            wg_bump(&cA, lane);
        }
    } else {
        // ================= group B: layer B, steps 0..63 =================
        for (int t = 0; t < TT; ++t) {
            const int pb = t & 1;
            const int rsl = t & 3;          // ring slot holding h_A(t)
            if (t) wg_wait(&cB, 4 * t);
            // ---- own-h preload first (guarded by cB), issues during the cA window ----
            bf16x8 ahi[4], alo[4];
#pragma unroll
            for (int kt = 2; kt < 4; ++kt) {
                const int aoff = l16 * RS + (kt - 2) * 32 + quad * 8;
                ahi[kt] = *(const bf16x8*)&pHh[pb ^ 1][aoff];
                alo[kt] = *(const bf16x8*)&pHl[pb ^ 1][aoff];
            }
            wg_wait(&cA, 4 * (t + 1));      // h_A(t) complete (pre-satisfied when lagging)
#pragma unroll
            for (int kt = 0; kt < 2; ++kt) {
                const int aoff = l16 * RS + kt * 32 + quad * 8;
                ahi[kt] = *(const bf16x8*)&rHh[rsl][aoff];
                alo[kt] = *(const bf16x8*)&rHl[rsl][aoff];
            }
            wg_bump(&cBm, lane);   // release: A may overwrite ring slot rsl (at t+4)
            f32x4 a0[4], a1[4], a2[4];
#pragma unroll
            for (int gt = 0; gt < 4; ++gt) {
                a0[gt][0] = bsum[gt]; a0[gt][1] = bsum[gt];
                a0[gt][2] = bsum[gt]; a0[gt][3] = bsum[gt];
                a1[gt] = (f32x4){0.f, 0.f, 0.f, 0.f};
                a2[gt] = (f32x4){0.f, 0.f, 0.f, 0.f};
            }
            __builtin_amdgcn_s_setprio(1);
#pragma unroll
            for (int kt = 0; kt < 4; ++kt) {
#pragma unroll
                for (int gt = 0; gt < 4; ++gt) {
                    a0[gt] = __builtin_amdgcn_mfma_f32_16x16x32_bf16(ahi[kt], bhi[kt][gt], a0[gt], 0, 0, 0);
                    a1[gt] = __builtin_amdgcn_mfma_f32_16x16x32_bf16(alo[kt], bhi[kt][gt], a1[gt], 0, 0, 0);
                    a2[gt] = __builtin_amdgcn_mfma_f32_16x16x32_bf16(ahi[kt], blo[kt][gt], a2[gt], 0, 0, 0);
                }
            }
            __builtin_amdgcn_s_setprio(0);
            f32x4 s4[4];
#pragma unroll
            for (int gt = 0; gt < 4; ++gt) s4[gt] = (a0[gt] + a1[gt]) + a2[gt];
            float gk[4][2];
#pragma unroll
            for (int gt = 0; gt < 4; ++gt) {
#pragma unroll
                for (int r = 0; r < 2; ++r) {
                    const float up = __uint_as_float(
                        __builtin_amdgcn_ds_bpermute(bpi, __float_as_uint(s4[gt][r + 2])));
                    gk[gt][r] = lo32 ? s4[gt][r] : up;
                }
            }
#pragma unroll
            for (int r = 0; r < 2; ++r) {
                const float iv = sigmoid_fast(gk[0][r]);
                const float fv = sigmoid_fast(gk[1][r]);
                const float gv = tanh_fast(gk[2][r]);
                const float ov = sigmoid_fast(gk[3][r]);
                const float cn = fv * cs[r] + iv * gv;
                cs[r] = cn;
                const float h = ov * tanh_fast(cn);
                const int R = row0 + r;
                unsigned short h_, l_;
                split2(h, h_, l_);
                pHh[pb][R * RS + jg] = h_;   // h_B(t) recurrence
                pHl[pb][R * RS + jg] = l_;
                if (!last) {
                    P[((size_t)(base + R) * TT + t) * 64 + jg] =
                        ((unsigned)h_ << 16) | (unsigned)l_;
                } else {
                    houtf[((size_t)(base + R) * TT + t) * HH + jg] = h;
                }
            }
            wg_bump(&cB, lane);
        }
    }
}

// ---------------- output MLP: 64 -> 32 relu -> 4 ----------------
__global__ __launch_bounds__(256)
void mlp_out_kernel(const float* __restrict__ hin,
                    const float* __restrict__ wo1, const float* __restrict__ bo1,
                    const float* __restrict__ wo2, const float* __restrict__ bo2,
                    float* __restrict__ out) {
    __shared__ __align__(16) float wo1_s[32 * 64];
    __shared__ float bo1_s[32];
    __shared__ float wo2_s[4 * 32];
    __shared__ float bo2_s[4];
    const int tid = threadIdx.x;
    for (int e = tid; e < 32 * 64; e += 256) wo1_s[e] = wo1[e];
    if (tid < 32) bo1_s[tid] = bo1[tid];
    if (tid < 128) wo2_s[tid] = wo2[tid];
    if (tid < 4) bo2_s[tid] = bo2[tid];
    __syncthreads();

    const int gid = blockIdx.x * 256 + tid;
    const float4* hv = (const float4*)(hin + gid * 64);
    float4 h[16];
#pragma unroll
    for (int q = 0; q < 16; ++q) h[q] = hv[q];

    float m1[32];
#pragma unroll
    for (int o = 0; o < 32; ++o) {
        float acc = bo1_s[o];
        const float4* wrow = (const float4*)(wo1_s + o * 64);
#pragma unroll
        for (int q = 0; q < 16; ++q) {
            const float4 w = wrow[q];
            acc = fmaf(h[q].x, w.x, acc);
            acc = fmaf(h[q].y, w.y, acc);
            acc = fmaf(h[q].z, w.z, acc);
            acc = fmaf(h[q].w, w.w, acc);
        }
        m1[o] = fmaxf(0.f, acc);
    }
    float r[4];
#pragma unroll
    for (int q = 0; q < 4; ++q) {
        float acc = bo2_s[q];
#pragma unroll
        for (int o = 0; o < 32; ++o) acc = fmaf(m1[o], wo2_s[q * 32 + o], acc);
        r[q] = acc;
    }
    float4 res;
    res.x = r[0]; res.y = r[1]; res.z = r[2]; res.w = r[3];
    ((float4*)out)[gid] = res;
}

extern "C" void kernel_launch(void* const* d_in, const int* in_sizes, int n_in,
                              void* d_out, int out_size, void* d_ws, size_t ws_size,
                              hipStream_t stream) {
    const float* x     = (const float*)d_in[0];
    const float* w1    = (const float*)d_in[1];
    const float* b1    = (const float*)d_in[2];
    const float* w2    = (const float*)d_in[3];
    const float* b2    = (const float*)d_in[4];
    const float* w_ih0 = (const float*)d_in[5];
    const float* w_hh0 = (const float*)d_in[6];
    const float* b_ih0 = (const float*)d_in[7];
    const float* b_hh0 = (const float*)d_in[8];
    const float* w_ih  = (const float*)d_in[9];
    const float* w_hh  = (const float*)d_in[10];
    const float* b_ih  = (const float*)d_in[11];
    const float* b_hh  = (const float*)d_in[12];
    const float* wo1   = (const float*)d_in[13];
    const float* bo1   = (const float*)d_in[14];
    const float* wo2   = (const float*)d_in[15];
    const float* bo2   = (const float*)d_in[16];

    // workspace: buf_mlp B*T*16 f32 (8 MB) | P B*T*64 u32 packed (32 MB) | bufH B*T*64 f32 (32 MB)
    float* buf_mlp = (float*)d_ws;
    unsigned* P = (unsigned*)(buf_mlp + (size_t)BATCH * TT * 16);
    float* bufH = (float*)(P + (size_t)BATCH * TT * 64);

    const int nbt_blocks = (BATCH * TT) / 256;  // 512

    mlp_in_kernel<<<nbt_blocks, 256, 0, stream>>>(x, w1, b1, w2, b2, buf_mlp);

    // pair 0: layers 0,1
    lstm_pair<16, 32><<<BATCH / 8, 512, 0, stream>>>(
        buf_mlp, P, bufH, 0,
        w_ih0, w_hh0, b_ih0, b_hh0,
        w_ih + (size_t)0 * 256 * 64, w_hh + (size_t)0 * 256 * 64, b_ih + 0 * 256, b_hh + 0 * 256);

    // pairs 1..3: layers (2,3), (4,5), (6,7) -> w_ih/w_hh indices (1,2), (3,4), (5,6)
    for (int p = 1; p < 4; ++p) {
        const int la = 2 * p - 1, lb = 2 * p;  // indices into w_ih/w_hh arrays (layer l -> idx l-1)
        lstm_pair<64, 64><<<BATCH / 8, 512, 0, stream>>>(
            buf_mlp, P, bufH, (p == 3) ? 1 : 0,
            w_ih + (size_t)la * 256 * 64, w_hh + (size_t)la * 256 * 64,
            b_ih + la * 256, b_hh + la * 256,
            w_ih + (size_t)lb * 256 * 64, w_hh + (size_t)lb * 256 * 64,
            b_ih + lb * 256, b_hh + lb * 256);
    }

    mlp_out_kernel<<<nbt_blocks, 256, 0, stream>>>(bufH, wo1, bo1, wo2, bo2, (float*)d_out);
}